// Round 7
// baseline (16.707 us; speedup 1.0000x reference)
//
#include <hip/hip_runtime.h>

#define PLACEHOLDER (-1)
#define TINY_F 1.17549435e-38f
#define MAXS 32
#define SPLIT_G 16
#define SPLIT_R 32

__device__ __forceinline__ void amax_combine(float& bv, int& bi, float v, int i) {
    // jnp.argmax: first occurrence wins ties -> prefer smaller index on equal value
    if (v > bv || (v == bv && i < bi)) { bv = v; bi = i; }
}

__device__ __forceinline__ unsigned long long pack_vi(float v, int i) {
    // positive floats order like their bit patterns; ~index gives min-index tie-break
    return ((unsigned long long)__float_as_uint(v) << 32) |
           (unsigned long long)(0xFFFFFFFFu - (unsigned)i);
}

__device__ __forceinline__ int unpack_idx(unsigned long long p) {
    return (int)(0xFFFFFFFFu - (unsigned)(p & 0xFFFFFFFFull));
}

// 256-thread block argmax; result on thread 0. Block-uniform control flow.
__device__ __forceinline__ void block_argmax(float& bv, int& bi) {
    for (int off = 32; off > 0; off >>= 1) {
        float ov = __shfl_down(bv, off, 64);
        int   oi = __shfl_down(bi, off, 64);
        amax_combine(bv, bi, ov, oi);
    }
    __shared__ float sv[8];
    __shared__ int   si[8];
    int lane = threadIdx.x & 63;
    int w    = threadIdx.x >> 6;
    if (lane == 0) { sv[w] = bv; si[w] = bi; }
    __syncthreads();
    if (threadIdx.x == 0) {
        int nw = (blockDim.x + 63) >> 6;
        for (int k = 1; k < nw; ++k) amax_combine(bv, bi, sv[k], si[k]);
    }
}

// single-wave (64-lane) argmax with broadcast to all lanes
__device__ __forceinline__ void wave_argmax_bcast(float& bv, int& bi) {
    for (int off = 32; off > 0; off >>= 1) {
        float ov = __shfl_down(bv, off, 64);
        int   oi = __shfl_down(bi, off, 64);
        amax_combine(bv, bi, ov, oi);
    }
    bv = __shfl(bv, 0, 64);
    bi = __shfl(bi, 0, 64);
}

// Kernel 1: parallel scans, private-slot partials (plain stores, no atomics).
//   blocks [0, B*SPLIT_R)         : recovered-argmax chunk (longest serial prefix
//                                   -> dispatched FIRST); split 0 writes ws_fr +
//                                   the full non-greedy output row.
//   blocks [B*SPLIT_R, +B*SPLIT_G): greedy-row target-argmax at p=0; split 0
//                                   pre-writes the PH tail of the output row.
// Greedy p>0 argmaxes (only needed if a greedy row accepts at p=0; ~1/V chance)
// are handled by k_final's cold path.
__global__ void k_main(const float* __restrict__ target_probs,
                       const float* __restrict__ draft_probs,
                       const float* __restrict__ exp_q,
                       const int* __restrict__ draft_ids,
                       const float* __restrict__ uniform,
                       const int* __restrict__ bonus,
                       const int* __restrict__ is_greedy,
                       unsigned long long* __restrict__ ws_g,   // B*SPLIT_G
                       unsigned long long* __restrict__ ws_r,   // B*SPLIT_R
                       int* __restrict__ ws_fr,                 // B
                       int* __restrict__ out,
                       int B, int S, int V) {
    int total_r = B * SPLIT_R;
    int tid = threadIdx.x;

    if ((int)blockIdx.x < total_r) {
        int b = blockIdx.x / SPLIT_R;
        int split = blockIdx.x - b * SPLIT_R;
        if (is_greedy[b]) return;

        int chunk = ((V + SPLIT_R - 1) / SPLIT_R + 3) & ~3;
        int begin = split * chunk;
        int end = begin + chunk; if (end > V) end = V;
        bool has_work = begin < end;

        // --- prefetch exp_q chunk (fr-independent addresses) into registers ---
        const float* erow = exp_q + (size_t)b * V;
        int nj = has_work ? (((end - begin) & ~3) >> 2) : 0;  // # float4 in chunk
        const float4* e4 = (const float4*)(erow + begin);
        float4 ea = make_float4(0.f, 0.f, 0.f, 0.f), eb = ea;
        if (tid < nj) ea = e4[tid];
        if (tid + (int)blockDim.x < nj) eb = e4[tid + blockDim.x];

        // --- redundant first-reject computation (block-uniform via LDS) ---
        __shared__ int s_tok[MAXS];
        __shared__ unsigned char s_acc[MAXS];
        __shared__ int s_fr;
        if (tid < S) {
            int tok = draft_ids[b * S + tid];
            s_tok[tid] = tok;
            bool acc = false;
            if (tok != PLACEHOLDER) {
                float tp = target_probs[(size_t)b * (S + 1) * V + (size_t)tid * V + tok];
                float dp = draft_probs[(size_t)b * S * V + (size_t)tid * V + tok];
                acc = (tp / dp) >= uniform[b * S + tid];
            }
            s_acc[tid] = acc ? 1 : 0;
        }
        __syncthreads();
        if (tid == 0) {
            int fr = -1;
            for (int q = 0; q < S; ++q) {
                if (s_tok[q] == PLACEHOLDER) break;
                if (!s_acc[q]) { fr = q; break; }
            }
            s_fr = fr;
        }
        __syncthreads();
        int fr = s_fr;

        // --- split 0 finalizes the non-greedy output row ---
        if (split == 0 && tid == 0) {
            ws_fr[b] = fr;
            int ob = b * (S + 1);
            if (fr < 0) {
                int ng = 0;
                for (int p = 0; p < S; ++p) {
                    if (s_tok[p] == PLACEHOLDER) break;
                    out[ob + p] = s_tok[p];
                    ++ng;
                }
                for (int q = ng; q <= S; ++q) out[ob + q] = PLACEHOLDER;
                out[ob + ng] = bonus[b];
            } else {
                for (int p = 0; p < fr; ++p) out[ob + p] = s_tok[p];
                for (int q = fr; q <= S; ++q) out[ob + q] = PLACEHOLDER;
                // out[ob+fr] patched by k_final; bonus slot stays PLACEHOLDER
            }
        }
        if (fr < 0 || !has_work) return;

        // --- recovered-argmax scan of this chunk (1 float4/thread/array) ---
        const float* trow = target_probs + (size_t)b * (S + 1) * V + (size_t)fr * V;
        const float* drow = draft_probs + (size_t)b * S * V + (size_t)fr * V;
        const float4* t4 = (const float4*)(trow + begin);
        const float4* d4 = (const float4*)(drow + begin);
        float bv = 0.0f; int bi = 0x7fffffff;
        if (tid < nj) {
            float4 tt = t4[tid], dd = d4[tid];
            int base = begin + (tid << 2);
            amax_combine(bv, bi, fmaxf(tt.x - dd.x, TINY_F) / ea.x, base);
            amax_combine(bv, bi, fmaxf(tt.y - dd.y, TINY_F) / ea.y, base + 1);
            amax_combine(bv, bi, fmaxf(tt.z - dd.z, TINY_F) / ea.z, base + 2);
            amax_combine(bv, bi, fmaxf(tt.w - dd.w, TINY_F) / ea.w, base + 3);
        }
        if (tid + (int)blockDim.x < nj) {
            int j = tid + blockDim.x;
            float4 tt = t4[j], dd = d4[j];
            int base = begin + (j << 2);
            amax_combine(bv, bi, fmaxf(tt.x - dd.x, TINY_F) / eb.x, base);
            amax_combine(bv, bi, fmaxf(tt.y - dd.y, TINY_F) / eb.y, base + 1);
            amax_combine(bv, bi, fmaxf(tt.z - dd.z, TINY_F) / eb.z, base + 2);
            amax_combine(bv, bi, fmaxf(tt.w - dd.w, TINY_F) / eb.w, base + 3);
        }
        for (int j = tid + 2 * blockDim.x; j < nj; j += blockDim.x) {  // generic spill
            float4 tt = t4[j], dd = d4[j], ee = e4[j];
            int base = begin + (j << 2);
            amax_combine(bv, bi, fmaxf(tt.x - dd.x, TINY_F) / ee.x, base);
            amax_combine(bv, bi, fmaxf(tt.y - dd.y, TINY_F) / ee.y, base + 1);
            amax_combine(bv, bi, fmaxf(tt.z - dd.z, TINY_F) / ee.z, base + 2);
            amax_combine(bv, bi, fmaxf(tt.w - dd.w, TINY_F) / ee.w, base + 3);
        }
        for (int j = begin + (nj << 2) + tid; j < end; j += blockDim.x)  // scalar tail
            amax_combine(bv, bi, fmaxf(trow[j] - drow[j], TINY_F) / erow[j], j);
        block_argmax(bv, bi);
        if (tid == 0) ws_r[(size_t)b * SPLIT_R + split] = pack_vi(bv, bi);
    } else {
        int t = blockIdx.x - total_r;
        int b = t / SPLIT_G;
        int split = t - b * SPLIT_G;
        if (!is_greedy[b]) return;
        if (draft_ids[b * S] == PLACEHOLDER) return;

        // split 0 pre-writes the PH tail (hot path: reject at p=0)
        if (split == 0 && tid == 0) {
            int ob = b * (S + 1);
            for (int q = 1; q <= S; ++q) out[ob + q] = PLACEHOLDER;
        }

        int chunk = ((V + SPLIT_G - 1) / SPLIT_G + 3) & ~3;
        int begin = split * chunk;
        int end = begin + chunk; if (end > V) end = V;
        if (begin >= end) return;

        const float* row = target_probs + (size_t)b * (S + 1) * V;  // p = 0
        float bv = 0.0f; int bi = 0x7fffffff;
        int vend = begin + ((end - begin) & ~3);
        const float4* r4 = (const float4*)row;
        for (int j = (begin >> 2) + tid; j < (vend >> 2); j += blockDim.x) {
            float4 f = r4[j];
            int base = j << 2;
            amax_combine(bv, bi, f.x, base);
            amax_combine(bv, bi, f.y, base + 1);
            amax_combine(bv, bi, f.z, base + 2);
            amax_combine(bv, bi, f.w, base + 3);
        }
        for (int j = vend + tid; j < end; j += blockDim.x)
            amax_combine(bv, bi, row[j], j);
        block_argmax(bv, bi);
        if (tid == 0) ws_g[(size_t)b * SPLIT_G + split] = pack_vi(bv, bi);
    }
}

// Kernel 2: one wave per row. Greedy hot path: merge p=0 partials, 1-2 stores
// (cold-path full row rebuild if greedy row accepts p=0). Non-greedy: patch token.
__global__ void k_final(const int* __restrict__ draft_ids,
                        const float* __restrict__ target_probs,
                        const int* __restrict__ bonus,
                        const int* __restrict__ is_greedy,
                        const unsigned long long* __restrict__ ws_g,
                        const unsigned long long* __restrict__ ws_r,
                        const int* __restrict__ ws_fr,
                        int* __restrict__ out,
                        int B, int S, int V) {
    int b = blockIdx.x;
    int lane = threadIdx.x;            // 64 threads = 1 wave
    int ob = b * (S + 1);

    if (is_greedy[b]) {
        // merge p=0 partials across lanes
        unsigned long long gm = 0ull;
        {
            int chunk = ((V + SPLIT_G - 1) / SPLIT_G + 3) & ~3;
            if (lane < SPLIT_G && lane * chunk < V)
                gm = ws_g[(size_t)b * SPLIT_G + lane];
        }
        for (int off = SPLIT_G / 2; off > 0; off >>= 1) {
            unsigned long long o = __shfl_down(gm, off, 64);
            if (o > gm) gm = o;
        }
        gm = __shfl(gm, 0, 64);
        int am0 = unpack_idx(gm);
        int tok0 = draft_ids[b * S];

        if (tok0 != am0) {
            // hot path: reject at p=0; tail already PH from k_main
            if (lane == 0) out[ob] = am0;
            return;
        }

        // cold path: greedy accepted at p=0 -> rebuild row with full scans
        int p = 0, ng = 0;
        bool rej = false;
        while (p < S) {
            int tok = draft_ids[b * S + p];
            if (tok == PLACEHOLDER) break;
            int am;
            if (p == 0) {
                am = am0;
            } else {
                const float* row = target_probs + (size_t)b * (S + 1) * V + (size_t)p * V;
                float bv = 0.0f; int bi = 0x7fffffff;
                int nv4 = V >> 2;
                const float4* r4 = (const float4*)row;
                for (int j = lane; j < nv4; j += 64) {
                    float4 f = r4[j];
                    int base = j << 2;
                    amax_combine(bv, bi, f.x, base);
                    amax_combine(bv, bi, f.y, base + 1);
                    amax_combine(bv, bi, f.z, base + 2);
                    amax_combine(bv, bi, f.w, base + 3);
                }
                for (int j = (nv4 << 2) + lane; j < V; j += 64)
                    amax_combine(bv, bi, row[j], j);
                wave_argmax_bcast(bv, bi);
                am = bi;
            }
            bool acc = (tok == am);
            if (lane == 0) out[ob + p] = acc ? tok : am;
            ++ng;
            if (!acc) { rej = true; break; }
            ++p;
        }
        if (lane == 0) {
            for (int q = ng; q <= S; ++q) out[ob + q] = PLACEHOLDER;
            if (!rej) out[ob + ng] = bonus[b];
        }
    } else {
        int fr = ws_fr[b];
        if (fr < 0) return;   // row fully written by k_main
        unsigned long long rm = 0ull;
        {
            int chunk = ((V + SPLIT_R - 1) / SPLIT_R + 3) & ~3;
            if (lane < SPLIT_R && lane * chunk < V)
                rm = ws_r[(size_t)b * SPLIT_R + lane];
        }
        for (int off = SPLIT_R / 2; off > 0; off >>= 1) {
            unsigned long long o = __shfl_down(rm, off, 64);
            if (o > rm) rm = o;
        }
        if (lane == 0) out[ob + fr] = unpack_idx(rm);
    }
}

extern "C" void kernel_launch(void* const* d_in, const int* in_sizes, int n_in,
                              void* d_out, int out_size, void* d_ws, size_t ws_size,
                              hipStream_t stream) {
    const int*   draft_ids    = (const int*)d_in[0];
    const float* draft_probs  = (const float*)d_in[1];
    const float* target_probs = (const float*)d_in[2];
    const int*   bonus        = (const int*)d_in[3];
    const float* uniform      = (const float*)d_in[4];
    const float* exp_q        = (const float*)d_in[5];
    const int*   is_greedy    = (const int*)d_in[6];

    int B = in_sizes[6];           // 128
    int S = in_sizes[4] / B;       // 8
    int V = in_sizes[5] / B;       // 32000

    unsigned long long* ws_g = (unsigned long long*)d_ws;      // B*SPLIT_G
    unsigned long long* ws_r = ws_g + (size_t)B * SPLIT_G;     // B*SPLIT_R
    int* ws_fr = (int*)(ws_r + (size_t)B * SPLIT_R);           // B
    int* out = (int*)d_out;

    int grid = B * SPLIT_R + B * SPLIT_G;
    k_main<<<grid, 256, 0, stream>>>(target_probs, draft_probs, exp_q, draft_ids,
                                     uniform, bonus, is_greedy,
                                     ws_g, ws_r, ws_fr, out, B, S, V);
    k_final<<<B, 64, 0, stream>>>(draft_ids, target_probs, bonus, is_greedy,
                                  ws_g, ws_r, ws_fr, out, B, S, V);
}

// Round 8
// 15.023 us; speedup vs baseline: 1.1121x; 1.1121x over previous
//
#include <hip/hip_runtime.h>

#define PLACEHOLDER (-1)
#define TINY_F 1.17549435e-38f
#define MAXS 32
#define SPLIT_G 8
#define SPLIT_R 16

__device__ __forceinline__ void amax_combine(float& bv, int& bi, float v, int i) {
    // jnp.argmax: first occurrence wins ties -> prefer smaller index on equal value
    if (v > bv || (v == bv && i < bi)) { bv = v; bi = i; }
}

__device__ __forceinline__ unsigned long long pack_vi(float v, int i) {
    // positive floats order like their bit patterns; ~index gives min-index tie-break
    return ((unsigned long long)__float_as_uint(v) << 32) |
           (unsigned long long)(0xFFFFFFFFu - (unsigned)i);
}

__device__ __forceinline__ int unpack_idx(unsigned long long p) {
    return (int)(0xFFFFFFFFu - (unsigned)(p & 0xFFFFFFFFull));
}

// 256-thread block argmax; result on thread 0. Block-uniform control flow.
__device__ __forceinline__ void block_argmax(float& bv, int& bi) {
    for (int off = 32; off > 0; off >>= 1) {
        float ov = __shfl_down(bv, off, 64);
        int   oi = __shfl_down(bi, off, 64);
        amax_combine(bv, bi, ov, oi);
    }
    __shared__ float sv[8];
    __shared__ int   si[8];
    int lane = threadIdx.x & 63;
    int w    = threadIdx.x >> 6;
    if (lane == 0) { sv[w] = bv; si[w] = bi; }
    __syncthreads();
    if (threadIdx.x == 0) {
        int nw = (blockDim.x + 63) >> 6;
        for (int k = 1; k < nw; ++k) amax_combine(bv, bi, sv[k], si[k]);
    }
}

// single-wave (64-lane) argmax with broadcast to all lanes
__device__ __forceinline__ void wave_argmax_bcast(float& bv, int& bi) {
    for (int off = 32; off > 0; off >>= 1) {
        float ov = __shfl_down(bv, off, 64);
        int   oi = __shfl_down(bi, off, 64);
        amax_combine(bv, bi, ov, oi);
    }
    bv = __shfl(bv, 0, 64);
    bi = __shfl(bi, 0, 64);
}

// Kernel 1: parallel scans, private-slot partials (plain stores, no atomics).
//   blocks [0, B*SPLIT_G)         : greedy-row target-argmax at p=0 only; split 0
//                                   pre-writes the PH tail of the output row.
//   blocks [B*SPLIT_G, +B*SPLIT_R): recovered-argmax chunk; split 0 writes ws_fr +
//                                   the full non-greedy output row.
// Greedy p>0 argmaxes (only needed if a greedy row accepts at p=0; ~1/V chance)
// are handled by k_final's cold path.
__global__ void k_main(const float* __restrict__ target_probs,
                       const float* __restrict__ draft_probs,
                       const float* __restrict__ exp_q,
                       const int* __restrict__ draft_ids,
                       const float* __restrict__ uniform,
                       const int* __restrict__ bonus,
                       const int* __restrict__ is_greedy,
                       unsigned long long* __restrict__ ws_g,   // B*SPLIT_G
                       unsigned long long* __restrict__ ws_r,   // B*SPLIT_R
                       int* __restrict__ ws_fr,                 // B
                       int* __restrict__ out,
                       int B, int S, int V) {
    int total_g = B * SPLIT_G;
    int tid = threadIdx.x;

    if ((int)blockIdx.x < total_g) {
        int b = blockIdx.x / SPLIT_G;
        int split = blockIdx.x - b * SPLIT_G;
        if (!is_greedy[b]) return;
        if (draft_ids[b * S] == PLACEHOLDER) return;

        // split 0 pre-writes the PH tail (hot path in k_final: reject at p=0)
        if (split == 0 && tid == 0) {
            int ob = b * (S + 1);
            for (int q = 1; q <= S; ++q) out[ob + q] = PLACEHOLDER;
        }

        int chunk = ((V + SPLIT_G - 1) / SPLIT_G + 3) & ~3;
        int begin = split * chunk;
        int end = begin + chunk; if (end > V) end = V;
        if (begin >= end) return;

        const float* row = target_probs + (size_t)b * (S + 1) * V;  // p = 0
        float bv = 0.0f; int bi = 0x7fffffff;
        int vend = begin + ((end - begin) & ~3);
        const float4* r4 = (const float4*)row;
        for (int j = (begin >> 2) + tid; j < (vend >> 2); j += blockDim.x) {
            float4 f = r4[j];
            int base = j << 2;
            amax_combine(bv, bi, f.x, base);
            amax_combine(bv, bi, f.y, base + 1);
            amax_combine(bv, bi, f.z, base + 2);
            amax_combine(bv, bi, f.w, base + 3);
        }
        for (int j = vend + tid; j < end; j += blockDim.x)
            amax_combine(bv, bi, row[j], j);
        block_argmax(bv, bi);
        if (tid == 0) ws_g[(size_t)b * SPLIT_G + split] = pack_vi(bv, bi);
    } else {
        int t = blockIdx.x - total_g;
        int split = t % SPLIT_R;
        int b = t / SPLIT_R;
        if (is_greedy[b]) return;

        int chunk = ((V + SPLIT_R - 1) / SPLIT_R + 3) & ~3;
        int begin = split * chunk;
        int end = begin + chunk; if (end > V) end = V;
        bool has_work = begin < end;

        // --- prefetch exp_q chunk (fr-independent addresses) into registers ---
        const float* erow = exp_q + (size_t)b * V;
        int nj = has_work ? (((end - begin) & ~3) >> 2) : 0;  // # float4 in chunk
        const float4* e4 = (const float4*)(erow + begin);
        float4 ea = make_float4(0.f, 0.f, 0.f, 0.f), eb = ea;
        if (tid < nj) ea = e4[tid];
        if (tid + (int)blockDim.x < nj) eb = e4[tid + blockDim.x];

        // --- redundant first-reject computation (block-uniform via LDS) ---
        __shared__ int s_tok[MAXS];
        __shared__ unsigned char s_acc[MAXS];
        __shared__ int s_fr;
        if (tid < S) {
            int tok = draft_ids[b * S + tid];
            s_tok[tid] = tok;
            bool acc = false;
            if (tok != PLACEHOLDER) {
                float tp = target_probs[(size_t)b * (S + 1) * V + (size_t)tid * V + tok];
                float dp = draft_probs[(size_t)b * S * V + (size_t)tid * V + tok];
                acc = (tp / dp) >= uniform[b * S + tid];
            }
            s_acc[tid] = acc ? 1 : 0;
        }
        __syncthreads();
        if (tid == 0) {
            int fr = -1;
            for (int q = 0; q < S; ++q) {
                if (s_tok[q] == PLACEHOLDER) break;
                if (!s_acc[q]) { fr = q; break; }
            }
            s_fr = fr;
        }
        __syncthreads();
        int fr = s_fr;

        // --- split 0 finalizes the non-greedy output row ---
        if (split == 0 && tid == 0) {
            ws_fr[b] = fr;
            int ob = b * (S + 1);
            if (fr < 0) {
                int ng = 0;
                for (int p = 0; p < S; ++p) {
                    if (s_tok[p] == PLACEHOLDER) break;
                    out[ob + p] = s_tok[p];
                    ++ng;
                }
                for (int q = ng; q <= S; ++q) out[ob + q] = PLACEHOLDER;
                out[ob + ng] = bonus[b];
            } else {
                for (int p = 0; p < fr; ++p) out[ob + p] = s_tok[p];
                for (int q = fr; q <= S; ++q) out[ob + q] = PLACEHOLDER;
                // out[ob+fr] patched by k_final; bonus slot stays PLACEHOLDER
            }
        }
        if (fr < 0 || !has_work) return;

        // --- recovered-argmax scan of this chunk ---
        const float* trow = target_probs + (size_t)b * (S + 1) * V + (size_t)fr * V;
        const float* drow = draft_probs + (size_t)b * S * V + (size_t)fr * V;
        const float4* t4 = (const float4*)(trow + begin);
        const float4* d4 = (const float4*)(drow + begin);
        float bv = 0.0f; int bi = 0x7fffffff;
        if (tid < nj) {
            float4 tt = t4[tid], dd = d4[tid];
            int base = begin + (tid << 2);
            amax_combine(bv, bi, fmaxf(tt.x - dd.x, TINY_F) / ea.x, base);
            amax_combine(bv, bi, fmaxf(tt.y - dd.y, TINY_F) / ea.y, base + 1);
            amax_combine(bv, bi, fmaxf(tt.z - dd.z, TINY_F) / ea.z, base + 2);
            amax_combine(bv, bi, fmaxf(tt.w - dd.w, TINY_F) / ea.w, base + 3);
        }
        if (tid + (int)blockDim.x < nj) {
            int j = tid + blockDim.x;
            float4 tt = t4[j], dd = d4[j];
            int base = begin + (j << 2);
            amax_combine(bv, bi, fmaxf(tt.x - dd.x, TINY_F) / eb.x, base);
            amax_combine(bv, bi, fmaxf(tt.y - dd.y, TINY_F) / eb.y, base + 1);
            amax_combine(bv, bi, fmaxf(tt.z - dd.z, TINY_F) / eb.z, base + 2);
            amax_combine(bv, bi, fmaxf(tt.w - dd.w, TINY_F) / eb.w, base + 3);
        }
        for (int j = tid + 2 * blockDim.x; j < nj; j += blockDim.x) {  // generic spill
            float4 tt = t4[j], dd = d4[j], ee = e4[j];
            int base = begin + (j << 2);
            amax_combine(bv, bi, fmaxf(tt.x - dd.x, TINY_F) / ee.x, base);
            amax_combine(bv, bi, fmaxf(tt.y - dd.y, TINY_F) / ee.y, base + 1);
            amax_combine(bv, bi, fmaxf(tt.z - dd.z, TINY_F) / ee.z, base + 2);
            amax_combine(bv, bi, fmaxf(tt.w - dd.w, TINY_F) / ee.w, base + 3);
        }
        for (int j = begin + (nj << 2) + tid; j < end; j += blockDim.x)  // scalar tail
            amax_combine(bv, bi, fmaxf(trow[j] - drow[j], TINY_F) / erow[j], j);
        block_argmax(bv, bi);
        if (tid == 0) ws_r[(size_t)b * SPLIT_R + split] = pack_vi(bv, bi);
    }
}

// Kernel 2: one wave per row. Greedy hot path: merge p=0 partials -> 1 store
// (tail pre-written by k_main); cold path: full row rebuild with wave scans.
// Non-greedy: patch recovered token at fr.
__global__ void k_final(const int* __restrict__ draft_ids,
                        const float* __restrict__ target_probs,
                        const int* __restrict__ bonus,
                        const int* __restrict__ is_greedy,
                        const unsigned long long* __restrict__ ws_g,
                        const unsigned long long* __restrict__ ws_r,
                        const int* __restrict__ ws_fr,
                        int* __restrict__ out,
                        int B, int S, int V) {
    int b = blockIdx.x;
    int lane = threadIdx.x;            // 64 threads = 1 wave
    int ob = b * (S + 1);

    if (is_greedy[b]) {
        // merge p=0 partials across lanes
        unsigned long long gm = 0ull;
        {
            int chunk = ((V + SPLIT_G - 1) / SPLIT_G + 3) & ~3;
            if (lane < SPLIT_G && lane * chunk < V)
                gm = ws_g[(size_t)b * SPLIT_G + lane];
        }
        for (int off = SPLIT_G / 2; off > 0; off >>= 1) {
            unsigned long long o = __shfl_down(gm, off, 64);
            if (o > gm) gm = o;
        }
        gm = __shfl(gm, 0, 64);
        int am0 = unpack_idx(gm);
        int tok0 = draft_ids[b * S];

        if (tok0 != PLACEHOLDER && tok0 != am0) {
            // hot path: reject at p=0; PH tail pre-written by k_main
            if (lane == 0) out[ob] = am0;
            return;
        }

        // cold path: greedy accepted at p=0 (or empty row) -> rebuild full row
        int p = 0, ng = 0;
        bool rej = false;
        while (p < S) {
            int tok = draft_ids[b * S + p];
            if (tok == PLACEHOLDER) break;
            int am;
            if (p == 0) {
                am = am0;
            } else {
                const float* row = target_probs + (size_t)b * (S + 1) * V + (size_t)p * V;
                float bv = 0.0f; int bi = 0x7fffffff;
                int nv4 = V >> 2;
                const float4* r4 = (const float4*)row;
                for (int j = lane; j < nv4; j += 64) {
                    float4 f = r4[j];
                    int base = j << 2;
                    amax_combine(bv, bi, f.x, base);
                    amax_combine(bv, bi, f.y, base + 1);
                    amax_combine(bv, bi, f.z, base + 2);
                    amax_combine(bv, bi, f.w, base + 3);
                }
                for (int j = (nv4 << 2) + lane; j < V; j += 64)
                    amax_combine(bv, bi, row[j], j);
                wave_argmax_bcast(bv, bi);
                am = bi;
            }
            bool acc = (tok == am);
            if (lane == 0) out[ob + p] = acc ? tok : am;
            ++ng;
            if (!acc) { rej = true; break; }
            ++p;
        }
        if (lane == 0) {
            for (int q = ng; q <= S; ++q) out[ob + q] = PLACEHOLDER;
            if (!rej) out[ob + ng] = bonus[b];
        }
    } else {
        int fr = ws_fr[b];
        if (fr < 0) return;   // row fully written by k_main
        unsigned long long rm = 0ull;
        {
            int chunk = ((V + SPLIT_R - 1) / SPLIT_R + 3) & ~3;
            if (lane < SPLIT_R && lane * chunk < V)
                rm = ws_r[(size_t)b * SPLIT_R + lane];
        }
        for (int off = SPLIT_R / 2; off > 0; off >>= 1) {
            unsigned long long o = __shfl_down(rm, off, 64);
            if (o > rm) rm = o;
        }
        if (lane == 0) out[ob + fr] = unpack_idx(rm);
    }
}

extern "C" void kernel_launch(void* const* d_in, const int* in_sizes, int n_in,
                              void* d_out, int out_size, void* d_ws, size_t ws_size,
                              hipStream_t stream) {
    const int*   draft_ids    = (const int*)d_in[0];
    const float* draft_probs  = (const float*)d_in[1];
    const float* target_probs = (const float*)d_in[2];
    const int*   bonus        = (const int*)d_in[3];
    const float* uniform      = (const float*)d_in[4];
    const float* exp_q        = (const float*)d_in[5];
    const int*   is_greedy    = (const int*)d_in[6];

    int B = in_sizes[6];           // 128
    int S = in_sizes[4] / B;       // 8
    int V = in_sizes[5] / B;       // 32000

    unsigned long long* ws_g = (unsigned long long*)d_ws;      // B*SPLIT_G
    unsigned long long* ws_r = ws_g + (size_t)B * SPLIT_G;     // B*SPLIT_R
    int* ws_fr = (int*)(ws_r + (size_t)B * SPLIT_R);           // B
    int* out = (int*)d_out;

    int grid = B * SPLIT_G + B * SPLIT_R;
    k_main<<<grid, 256, 0, stream>>>(target_probs, draft_probs, exp_q, draft_ids,
                                     uniform, bonus, is_greedy,
                                     ws_g, ws_r, ws_fr, out, B, S, V);
    k_final<<<B, 64, 0, stream>>>(draft_ids, target_probs, bonus, is_greedy,
                                  ws_g, ws_r, ws_fr, out, B, S, V);
}